// Round 12
// baseline (256.045 us; speedup 1.0000x reference)
//
#include <hip/hip_runtime.h>
#include <hip/hip_bf16.h>
#include <math.h>

// Problem constants
#define B_   4
#define N_   2048
#define DIM_ 1024
#define H_   16
#define DH_  64
#define E3_  3072   // 3*H*DH

typedef __attribute__((ext_vector_type(8)))  short s8v;   // 8 bf16 (4 VGPRs)
typedef __attribute__((ext_vector_type(4)))  float f4v;   // 16x16 MFMA accumulator
typedef __attribute__((ext_vector_type(16))) float f16v;  // 32x32 MFMA accumulator

// fast fp32->bf16: round-half-up (adds 0.5 ulp then truncate). 2 VALU ops.
__device__ __forceinline__ unsigned short f2bf_fast(float f) {
    return (unsigned short)((__builtin_bit_cast(unsigned int, f) + 0x8000u) >> 16);
}
// pack two fp32 -> two bf16 in one u32 via v_perm_b32 (3 VALU ops total)
__device__ __forceinline__ unsigned int pkbf(float a, float b) {
    unsigned int ua = __builtin_bit_cast(unsigned int, a) + 0x8000u;
    unsigned int ub = __builtin_bit_cast(unsigned int, b) + 0x8000u;
    return __builtin_amdgcn_perm(ub, ua, 0x07060302);
}
// single-instruction pack: dst.lo = bf16(a), dst.hi = bf16(b)  (RNE)
__device__ __forceinline__ unsigned int cvtpk(float a, float b) {
    unsigned int r;
    asm("v_cvt_pk_bf16_f32 %0, %1, %2" : "=v"(r) : "v"(a), "v"(b));
    return r;
}
// v_permlane32_swap_b32: after execution
//   a' = [a(lanes 0:31) | b(lanes 0:31)],  b' = [a(lanes 32:63) | b(lanes 32:63)]
__device__ __forceinline__ uint2 pl32(unsigned int a, unsigned int b) {
    asm volatile("v_permlane32_swap_b32 %0, %1" : "+v"(a), "+v"(b));
    return make_uint2(a, b);
}

// async global->LDS, 16 B per lane; LDS dest = wave-uniform base + lane*16
__device__ __forceinline__ void gload_lds16(const void* g, void* l) {
    __builtin_amdgcn_global_load_lds(
        (const __attribute__((address_space(1))) unsigned int*)(uintptr_t)g,
        (__attribute__((address_space(3))) unsigned int*)(uintptr_t)l,
        16, 0, 0);
}

// exp2 + cvt_pk + permlane32_swap: f32x16 S^T fragment -> two bf16x8 PV
// A-fragments (keys lo/hi 16-blocks). Verified layout (rounds 2-11).
__device__ __forceinline__ void pack_p(const f16v& st, s8v& a0, s8v& a1) {
    float pe[16];
    #pragma unroll
    for (int i = 0; i < 16; i++)
        pe[i] = __builtin_amdgcn_exp2f(st[i]);
    union { s8v v; unsigned int u[4]; } f0, f1;
    uint2 r;
    r = pl32(cvtpk(pe[0],  pe[1]),  cvtpk(pe[4],  pe[5]));
    f0.u[0] = r.x; f0.u[2] = r.y;
    r = pl32(cvtpk(pe[2],  pe[3]),  cvtpk(pe[6],  pe[7]));
    f0.u[1] = r.x; f0.u[3] = r.y;
    r = pl32(cvtpk(pe[8],  pe[9]),  cvtpk(pe[12], pe[13]));
    f1.u[0] = r.x; f1.u[2] = r.y;
    r = pl32(cvtpk(pe[10], pe[11]), cvtpk(pe[14], pe[15]));
    f1.u[1] = r.x; f1.u[3] = r.y;
    a0 = f0.v;   // keys base + 0..15
    a1 = f1.v;   // keys base + 16..31
}

// ---------------------------------------------------------------------------
// fused fp32 -> bf16 convert for all three inputs (1 dispatch)
// ---------------------------------------------------------------------------
__global__ __launch_bounds__(256) void cvt_all(
    const float* __restrict__ x,  const float* __restrict__ wq,
    const float* __restrict__ wo,
    unsigned short* __restrict__ xb, unsigned short* __restrict__ wqb,
    unsigned short* __restrict__ wob)
{
    const int bid = blockIdx.x;
    const float* in; unsigned short* out; int rb;
    if (bid < 8192)       { in = x;  out = xb;  rb = bid; }
    else if (bid < 11264) { in = wq; out = wqb; rb = bid - 8192; }
    else                  { in = wo; out = wob; rb = bid - 11264; }
    const int i = (rb * 256 + threadIdx.x) * 4;
    float4 v = *(const float4*)(in + i);
    uint2 pk;
    pk.x = pkbf(v.x, v.y);
    pk.y = pkbf(v.z, v.w);
    *(uint2*)(out + i) = pk;
}

// ---------------------------------------------------------------------------
// QKV projection GEMM v5 (round-11, CONTROL): 3-slot ring, counted vmcnt.
// (Neutral vs the 2-buffer version — kept; see round-11 notes.)
// BM256 x BN128 x BK64, 512 thr = 8 waves, wave tile 128x32, 144KB LDS.
// Q-third pre-scaled by 0.125*log2(e); V-third redirected to vT[b,h,d,n].
// ---------------------------------------------------------------------------
__global__ __launch_bounds__(512, 1) void gemm_qkv(
    const unsigned short* __restrict__ A,    // x_bf [8192][1024]
    const unsigned short* __restrict__ Bw,   // wqkv_bf [3072][1024]
    unsigned short* __restrict__ Cb,         // qkv bf16 [8192][3072]
    unsigned short* __restrict__ Vt)         // [B*H][64][2048]
{
    __shared__ unsigned short Ls[3][24576];  // 3-slot ring, 48KB each = 144KB

    const int tid  = threadIdx.x;
    const int w    = tid >> 6;          // 0..7
    const int lane = tid & 63;
    const int quad = lane >> 4;
    const int l15  = lane & 15;
    const int wm   = w & 1;             // M half (128 rows)
    const int wn   = w >> 1;            // N quarter (32 cols)

    const int lin = blockIdx.y * 24 + blockIdx.x;
    const int swz = (lin & 7) * 96 + (lin >> 3);
    const int m0  = (swz / 24) * 256;
    const int n0  = (swz % 24) * 128;

    const int r8  = lane >> 3;              // 0..7
    const int chk = (lane & 7) ^ r8;        // pre-swizzled source chunk

    f4v acc[8][2];
    #pragma unroll
    for (int i = 0; i < 8; i++)
        #pragma unroll
        for (int j = 0; j < 2; j++) acc[i][j] = (f4v){0.f, 0.f, 0.f, 0.f};

    #define QKV_STAGE(slot, kk)                                                 \
        _Pragma("unroll")                                                       \
        for (int j = 0; j < 6; j++) {                                           \
            const int u = w * 6 + j;                                            \
            const unsigned short* src = (u < 32)                                \
                ? A  + (size_t)(m0 + u * 8 + r8) * 1024 + (kk) + chk * 8        \
                : Bw + (size_t)(n0 + (u - 32) * 8 + r8) * 1024 + (kk) + chk * 8;\
            gload_lds16(src, &Ls[slot][u * 512]);                               \
        }

    QKV_STAGE(0, 0);
    QKV_STAGE(1, 64);
    asm volatile("s_waitcnt vmcnt(6)" ::: "memory");
    __builtin_amdgcn_s_barrier();
    __builtin_amdgcn_sched_barrier(0);

    for (int t = 0; t < 16; t++) {
        const int cur = t % 3;

        if (t + 2 < 16) { QKV_STAGE((t + 2) % 3, (t + 2) * 64); }

        #pragma unroll
        for (int s = 0; s < 2; s++) {
            s8v af[8], bf[2];
            #pragma unroll
            for (int ms = 0; ms < 8; ms++) {
                const int row = wm * 128 + ms * 16 + l15;
                af[ms] = *(const s8v*)&Ls[cur][row * 64 + (((s * 4 + quad) ^ (l15 & 7)) * 8)];
            }
            #pragma unroll
            for (int ns = 0; ns < 2; ns++) {
                const int row = 256 + wn * 32 + ns * 16 + l15;
                bf[ns] = *(const s8v*)&Ls[cur][row * 64 + (((s * 4 + quad) ^ (l15 & 7)) * 8)];
            }
            __builtin_amdgcn_s_setprio(1);
            #pragma unroll
            for (int ms = 0; ms < 8; ms++)
                #pragma unroll
                for (int ns = 0; ns < 2; ns++)
                    acc[ms][ns] = __builtin_amdgcn_mfma_f32_16x16x32_bf16(
                        af[ms], bf[ns], acc[ms][ns], 0, 0, 0);
            __builtin_amdgcn_s_setprio(0);
        }

        if (t + 2 < 16)      { asm volatile("s_waitcnt vmcnt(6)" ::: "memory"); }
        else if (t + 1 < 16) { asm volatile("s_waitcnt vmcnt(0)" ::: "memory"); }
        __builtin_amdgcn_s_barrier();
        __builtin_amdgcn_sched_barrier(0);
    }
    #undef QKV_STAGE

    #pragma unroll
    for (int ns = 0; ns < 2; ns++) {
        const int colb = n0 + wn * 32 + ns * 16;   // wave-uniform, 16-aligned
        if (colb < 2048) {
            const float mul = (colb < 1024) ? 0.18033688011112042f : 1.0f;
            #pragma unroll
            for (int ms = 0; ms < 8; ms++)
                #pragma unroll
                for (int r = 0; r < 4; r++) {
                    const int row = m0 + wm * 128 + ms * 16 + quad * 4 + r;
                    Cb[(size_t)row * E3_ + colb + l15] = f2bf_fast(acc[ms][ns][r] * mul);
                }
        } else {
            const int e = colb + l15 - 2048;
            const int hh = e >> 6, d = e & 63;       // wave-uniform head
            #pragma unroll
            for (int ms = 0; ms < 8; ms++) {
                const int row = m0 + wm * 128 + ms * 16 + quad * 4;  // 4-aligned
                const int bb = row >> 11, nn = row & 2047;
                uint2 pk;
                pk.x = pkbf(acc[ms][ns][0], acc[ms][ns][1]);
                pk.y = pkbf(acc[ms][ns][2], acc[ms][ns][3]);
                *(uint2*)&Vt[(((size_t)bb * 16 + hh) * 64 + d) * 2048 + nn] = pk;
            }
        }
    }
}

// ---------------------------------------------------------------------------
// out projection GEMM v4 (round-11, CONTROL): 3-slot ring, counted vmcnt.
// BM128 x BN256 x BK64, 512 thr = 8 waves, wave tile 64x64, 144KB LDS.
// ---------------------------------------------------------------------------
__global__ __launch_bounds__(512, 1) void gemm_out(
    const unsigned short* __restrict__ A,    // ao_bf [8192][1024]
    const unsigned short* __restrict__ Bw,   // wout_bf [1024][1024]
    const float* __restrict__ bias,
    float* __restrict__ Cf)                  // out fp32 [8192][1024]
{
    __shared__ unsigned short Ls[3][24576];  // 3-slot ring, 48KB each = 144KB

    const int tid  = threadIdx.x;
    const int w    = tid >> 6;          // 0..7
    const int lane = tid & 63;
    const int quad = lane >> 4;
    const int l15  = lane & 15;
    const int wm   = w & 1;             // M half (64 rows)
    const int wn   = w >> 1;            // N quarter (64 cols)

    const int lin = blockIdx.y * 4 + blockIdx.x;
    const int swz = (lin & 7) * 32 + (lin >> 3);
    const int m0  = (swz >> 2) * 128;
    const int n0  = (swz & 3) * 256;

    const int r8  = lane >> 3;              // 0..7
    const int chk = (lane & 7) ^ r8;        // pre-swizzled source chunk

    f4v acc[4][4];
    #pragma unroll
    for (int i = 0; i < 4; i++)
        #pragma unroll
        for (int j = 0; j < 4; j++) acc[i][j] = (f4v){0.f, 0.f, 0.f, 0.f};

    #define OUT_STAGE(slot, kk)                                                 \
        _Pragma("unroll")                                                       \
        for (int j = 0; j < 6; j++) {                                           \
            const int u = w * 6 + j;                                            \
            const unsigned short* src = (u < 16)                                \
                ? A  + (size_t)(m0 + u * 8 + r8) * 1024 + (kk) + chk * 8        \
                : Bw + (size_t)(n0 + (u - 16) * 8 + r8) * 1024 + (kk) + chk * 8;\
            gload_lds16(src, &Ls[slot][u * 512]);                               \
        }

    OUT_STAGE(0, 0);
    OUT_STAGE(1, 64);
    asm volatile("s_waitcnt vmcnt(6)" ::: "memory");
    __builtin_amdgcn_s_barrier();
    __builtin_amdgcn_sched_barrier(0);

    for (int t = 0; t < 16; t++) {
        const int cur = t % 3;

        if (t + 2 < 16) { OUT_STAGE((t + 2) % 3, (t + 2) * 64); }

        #pragma unroll
        for (int s = 0; s < 2; s++) {
            s8v af[4], bf[4];
            #pragma unroll
            for (int ms = 0; ms < 4; ms++) {
                const int row = wm * 64 + ms * 16 + l15;
                af[ms] = *(const s8v*)&Ls[cur][row * 64 + (((s * 4 + quad) ^ (l15 & 7)) * 8)];
            }
            #pragma unroll
            for (int ns = 0; ns < 4; ns++) {
                const int row = 128 + wn * 64 + ns * 16 + l15;
                bf[ns] = *(const s8v*)&Ls[cur][row * 64 + (((s * 4 + quad) ^ (l15 & 7)) * 8)];
            }
            __builtin_amdgcn_s_setprio(1);
            #pragma unroll
            for (int ms = 0; ms < 4; ms++)
                #pragma unroll
                for (int ns = 0; ns < 4; ns++)
                    acc[ms][ns] = __builtin_amdgcn_mfma_f32_16x16x32_bf16(
                        af[ms], bf[ns], acc[ms][ns], 0, 0, 0);
            __builtin_amdgcn_s_setprio(0);
        }

        if (t + 2 < 16)      { asm volatile("s_waitcnt vmcnt(6)" ::: "memory"); }
        else if (t + 1 < 16) { asm volatile("s_waitcnt vmcnt(0)" ::: "memory"); }
        __builtin_amdgcn_s_barrier();
        __builtin_amdgcn_sched_barrier(0);
    }
    #undef OUT_STAGE

    #pragma unroll
    for (int ns = 0; ns < 4; ns++) {
        const float bz = bias[n0 + wn * 64 + ns * 16 + l15];
        #pragma unroll
        for (int ms = 0; ms < 4; ms++)
            #pragma unroll
            for (int r = 0; r < 4; r++) {
                const int row = m0 + wm * 64 + ms * 16 + quad * 4 + r;
                Cf[(size_t)row * 1024 + n0 + wn * 64 + ns * 16 + l15] =
                    acc[ms][ns][r] + bz;
            }
    }
}

// ---------------------------------------------------------------------------
// MFMA flash attention v12: v7 + dual-QK software pipeline (T15 mechanism).
// v7 counters (81us): MfmaUtil 48 + VALUBusy 43 = 91% combined issue, VGPR
// only 60 -> compiler chose a minimal-register SERIAL schedule: QK(k0) ->
// pack(k0) -> PV(k0) -> QK(k1) -> pack(k1) -> PV(k1); during each VALU pack
// the wave's MFMA stream is empty, and 4 waves/SIMD only partially cover it.
// v12 reorders (same math): load ak for BOTH ksubs, run BOTH QK chains
// back-to-back (two independent 4-MFMA chains), then pack0 -> PV0, pack1 ->
// PV1. pack1's VALU is dependency-free during PV0's MFMAs (and vice versa),
// so the scheduler can overlap pipes within one wave. Costs ~+32 VGPR
// (st1 + ak1 live) - free, occupancy here is LDS-capped.
// qkv bf16 [m][3072] (Q pre-scaled by 0.125*log2e); vT[b*16+h][d][n] bf16.
// ---------------------------------------------------------------------------
__global__ __launch_bounds__(512, 4) void attn_mfma(
    const unsigned short* __restrict__ qkv,
    const unsigned short* __restrict__ vT,
    unsigned short* __restrict__ ao)
{
    __shared__ __align__(16) unsigned short Ks[2][64][64];   // [buf][key][d] swz
    __shared__ __align__(16) unsigned short Vs[2][64][64];   // [buf][d][key] swz

    const int tid  = threadIdx.x;
    const int w    = tid >> 6;          // 0..7
    const int lane = tid & 63;
    const int l31  = lane & 31;
    const int hi5  = lane >> 5;         // 0/1
    const int h8   = hi5 * 8;

    const int lin = blockIdx.y * 8 + blockIdx.x;
    const int swz = (lin & 7) * 64 + (lin >> 3);
    const int bx  = swz & 7;
    const int bh  = swz >> 3;
    const int b   = bh >> 4;
    const int h   = bh & 15;
    const int q0  = bx * 256;           // 256 q-rows per block
    const int qb  = q0 + w * 32;        // 32 q-rows per wave

    const unsigned short* qp  = qkv + (size_t)b * N_ * E3_ + (size_t)h * DH_;
    const unsigned short* kp  = qp + 1024;
    const unsigned short* vtp = vT + (size_t)bh * 64 * 2048;

    const int drow = lane >> 3;             // 0..7 within slice
    const int dchk = (lane & 7) ^ drow;     // pre-swizzled source chunk
    const int grow = w * 8 + drow;          // row 0..63 (grow&7 == drow)

    s8v bq[4];
    {
        const unsigned short* qrow = qp + (size_t)(qb + l31) * E3_;
        #pragma unroll
        for (int ks = 0; ks < 4; ks++)
            bq[ks] = *(const s8v*)(qrow + ks * 16 + h8);
    }

    s8v ones;
    #pragma unroll
    for (int i = 0; i < 8; i++) ones[i] = (short)0x3F80;

    const f16v fzero = {0.f,0.f,0.f,0.f,0.f,0.f,0.f,0.f,
                        0.f,0.f,0.f,0.f,0.f,0.f,0.f,0.f};
    f16v o0 = fzero, o1 = fzero;   // d = 0..31 / 32..63
    f16v lc = fzero;               // row-sums, layout-matched to o

    gload_lds16(kp  + (size_t)grow * E3_  + dchk * 8, &Ks[0][w * 8][0]);
    gload_lds16(vtp + (size_t)grow * 2048 + dchk * 8, &Vs[0][w * 8][0]);
    __syncthreads();   // vmcnt(0) drain + barrier

    for (int kt = 0; kt < N_ / 64; kt++) {
        const int cur = kt & 1;

        if (kt + 1 < N_ / 64) {
            const int kn = (kt + 1) * 64;
            gload_lds16(kp  + (size_t)(kn + grow) * E3_  + dchk * 8,
                        &Ks[cur ^ 1][w * 8][0]);
            gload_lds16(vtp + (size_t)grow * 2048 + kn + dchk * 8,
                        &Vs[cur ^ 1][w * 8][0]);
        }

        const int ksw = (l31 & 7) * 8;     // rows l31 and 32+l31: same &7
        const int vsw = ksw;

        // ---- K A-fragments for BOTH ksubs ----
        s8v ak0[4], ak1[4];
        #pragma unroll
        for (int ks = 0; ks < 4; ks++) {
            ak0[ks] = *(const s8v*)&Ks[cur][l31     ][(ks * 16 + h8) ^ ksw];
            ak1[ks] = *(const s8v*)&Ks[cur][32 + l31][(ks * 16 + h8) ^ ksw];
        }

        // ---- both QK chains back-to-back (independent -> pipe stays fed) --
        f16v st0 = fzero, st1 = fzero;
        __builtin_amdgcn_s_setprio(1);
        st0 = __builtin_amdgcn_mfma_f32_32x32x16_bf16(ak0[0], bq[0], st0, 0, 0, 0);
        st1 = __builtin_amdgcn_mfma_f32_32x32x16_bf16(ak1[0], bq[0], st1, 0, 0, 0);
        st0 = __builtin_amdgcn_mfma_f32_32x32x16_bf16(ak0[1], bq[1], st0, 0, 0, 0);
        st1 = __builtin_amdgcn_mfma_f32_32x32x16_bf16(ak1[1], bq[1], st1, 0, 0, 0);
        st0 = __builtin_amdgcn_mfma_f32_32x32x16_bf16(ak0[2], bq[2], st0, 0, 0, 0);
        st1 = __builtin_amdgcn_mfma_f32_32x32x16_bf16(ak1[2], bq[2], st1, 0, 0, 0);
        st0 = __builtin_amdgcn_mfma_f32_32x32x16_bf16(ak0[3], bq[3], st0, 0, 0, 0);
        st1 = __builtin_amdgcn_mfma_f32_32x32x16_bf16(ak1[3], bq[3], st1, 0, 0, 0);
        __builtin_amdgcn_s_setprio(0);

        // ---- pack0 -> PV0 (pack1's VALU overlaps PV0's MFMAs) ----
        s8v pa0[2], pa1[2];
        pack_p(st0, pa0[0], pa0[1]);

        #pragma unroll
        for (int j = 0; j < 2; j++) {
            const int kbase = j * 16 + h8;             // ksub 0
            s8v bv0 = *(const s8v*)&Vs[cur][l31     ][kbase ^ vsw];
            s8v bv1 = *(const s8v*)&Vs[cur][32 + l31][kbase ^ vsw];
            __builtin_amdgcn_s_setprio(1);
            o0 = __builtin_amdgcn_mfma_f32_32x32x16_bf16(pa0[j], bv0, o0, 0, 0, 0);
            o1 = __builtin_amdgcn_mfma_f32_32x32x16_bf16(pa0[j], bv1, o1, 0, 0, 0);
            lc = __builtin_amdgcn_mfma_f32_32x32x16_bf16(pa0[j], ones, lc, 0, 0, 0);
            __builtin_amdgcn_s_setprio(0);
        }

        pack_p(st1, pa1[0], pa1[1]);

        #pragma unroll
        for (int j = 0; j < 2; j++) {
            const int kbase = (2 + j) * 16 + h8;       // ksub 1
            s8v bv0 = *(const s8v*)&Vs[cur][l31     ][kbase ^ vsw];
            s8v bv1 = *(const s8v*)&Vs[cur][32 + l31][kbase ^ vsw];
            __builtin_amdgcn_s_setprio(1);
            o0 = __builtin_amdgcn_mfma_f32_32x32x16_bf16(pa1[j], bv0, o0, 0, 0, 0);
            o1 = __builtin_amdgcn_mfma_f32_32x32x16_bf16(pa1[j], bv1, o1, 0, 0, 0);
            lc = __builtin_amdgcn_mfma_f32_32x32x16_bf16(pa1[j], ones, lc, 0, 0, 0);
            __builtin_amdgcn_s_setprio(0);
        }

        __syncthreads();
    }

    {
        float inv[16];
        #pragma unroll
        for (int r = 0; r < 16; r++) inv[r] = 1.f / lc[r];
        #pragma unroll
        for (int r = 0; r < 16; r++) {
            const int qrow = qb + (r & 3) + 8 * (r >> 2) + 4 * hi5;
            const size_t base = ((size_t)b * N_ + qrow) * (H_ * DH_) + h * DH_;
            ao[base + l31]      = f2bf_fast(o0[r] * inv[r]);
            ao[base + 32 + l31] = f2bf_fast(o1[r] * inv[r]);
        }
    }
}

// ---------------------------------------------------------------------------
// Launch — 4 dispatches
// ---------------------------------------------------------------------------
extern "C" void kernel_launch(void* const* d_in, const int* in_sizes, int n_in,
                              void* d_out, int out_size, void* d_ws, size_t ws_size,
                              hipStream_t stream) {
    const float* x     = (const float*)d_in[0];   // [B,N,DIM]
    const float* w_qkv = (const float*)d_in[1];   // [3072, 1024]
    const float* w_out = (const float*)d_in[2];   // [1024, 1024]
    const float* b_out = (const float*)d_in[3];   // [1024]
    float* out = (float*)d_out;                   // [B,N,DIM] fp32

    char* ws = (char*)d_ws;
    unsigned short* x_bf    = (unsigned short*)(ws);                        // 16 MB
    unsigned short* wqkv_bf = (unsigned short*)(ws + (((size_t)16) << 20)); //  6 MB
    unsigned short* wout_bf = (unsigned short*)(ws + (((size_t)22) << 20)); //  2 MB
    unsigned short* qkv_bf  = (unsigned short*)(ws + (((size_t)24) << 20)); // 48 MB
    unsigned short* vT      = (unsigned short*)(ws + (((size_t)72) << 20)); // 16 MB
    unsigned short* ao_bf   = (unsigned short*)(ws + (((size_t)88) << 20)); // 16 MB

    const int M = B_ * N_;   // 8192

    // 0) fused input conversions fp32 -> bf16 (1 dispatch)
    cvt_all<<<12288, 256, 0, stream>>>(x, w_qkv, w_out, x_bf, wqkv_bf, wout_bf);

    // 1) QKV projection v5: 256x128x64 tiles, 3-slot ring (control)
    {
        dim3 grid(E3_ / 128, M / 256);   // (24, 32) = 768 blocks
        gemm_qkv<<<grid, 512, 0, stream>>>(x_bf, wqkv_bf, qkv_bf, vT);
    }
    // 2) attention v12: dual-QK software pipeline
    {
        dim3 grid(N_ / 256, B_ * H_);    // (8, 64) = 512 blocks
        attn_mfma<<<grid, 512, 0, stream>>>(qkv_bf, vT, ao_bf);
    }
    // 3) out projection v4: 128x256x64 tiles, 3-slot ring (control)
    {
        dim3 grid(DIM_ / 256, M / 128);  // (4, 64) = 256 blocks
        gemm_out<<<grid, 512, 0, stream>>>(ao_bf, wout_bf, b_out, out);
    }
    (void)in_sizes; (void)n_in; (void)out_size; (void)ws_size;
}

// Round 13
// 248.313 us; speedup vs baseline: 1.0311x; 1.0311x over previous
//
#include <hip/hip_runtime.h>
#include <hip/hip_bf16.h>
#include <math.h>

// Problem constants
#define B_   4
#define N_   2048
#define DIM_ 1024
#define H_   16
#define DH_  64
#define E3_  3072   // 3*H*DH

typedef __attribute__((ext_vector_type(8)))  short s8v;   // 8 bf16 (4 VGPRs)
typedef __attribute__((ext_vector_type(4)))  float f4v;   // 16x16 MFMA accumulator
typedef __attribute__((ext_vector_type(16))) float f16v;  // 32x32 MFMA accumulator

// fast fp32->bf16: round-half-up (adds 0.5 ulp then truncate). 2 VALU ops.
__device__ __forceinline__ unsigned short f2bf_fast(float f) {
    return (unsigned short)((__builtin_bit_cast(unsigned int, f) + 0x8000u) >> 16);
}
// pack two fp32 -> two bf16 in one u32 via v_perm_b32 (3 VALU ops total)
__device__ __forceinline__ unsigned int pkbf(float a, float b) {
    unsigned int ua = __builtin_bit_cast(unsigned int, a) + 0x8000u;
    unsigned int ub = __builtin_bit_cast(unsigned int, b) + 0x8000u;
    return __builtin_amdgcn_perm(ub, ua, 0x07060302);
}
// single-instruction pack: dst.lo = bf16(a), dst.hi = bf16(b)  (RNE)
__device__ __forceinline__ unsigned int cvtpk(float a, float b) {
    unsigned int r;
    asm("v_cvt_pk_bf16_f32 %0, %1, %2" : "=v"(r) : "v"(a), "v"(b));
    return r;
}
// v_permlane32_swap_b32: after execution
//   a' = [a(lanes 0:31) | b(lanes 0:31)],  b' = [a(lanes 32:63) | b(lanes 32:63)]
__device__ __forceinline__ uint2 pl32(unsigned int a, unsigned int b) {
    asm volatile("v_permlane32_swap_b32 %0, %1" : "+v"(a), "+v"(b));
    return make_uint2(a, b);
}

// async global->LDS, 16 B per lane; LDS dest = wave-uniform base + lane*16
__device__ __forceinline__ void gload_lds16(const void* g, void* l) {
    __builtin_amdgcn_global_load_lds(
        (const __attribute__((address_space(1))) unsigned int*)(uintptr_t)g,
        (__attribute__((address_space(3))) unsigned int*)(uintptr_t)l,
        16, 0, 0);
}

// ---------------------------------------------------------------------------
// fused fp32 -> bf16 convert for all three inputs (1 dispatch instead of 3)
// blocks: [0,8192) x -> x_bf, [8192,11264) w_qkv -> wqkv_bf, rest w_out.
// All sizes are exact multiples of 1024 elements -> no bounds checks.
// ---------------------------------------------------------------------------
__global__ __launch_bounds__(256) void cvt_all(
    const float* __restrict__ x,  const float* __restrict__ wq,
    const float* __restrict__ wo,
    unsigned short* __restrict__ xb, unsigned short* __restrict__ wqb,
    unsigned short* __restrict__ wob)
{
    const int bid = blockIdx.x;
    const float* in; unsigned short* out; int rb;
    if (bid < 8192)       { in = x;  out = xb;  rb = bid; }
    else if (bid < 11264) { in = wq; out = wqb; rb = bid - 8192; }
    else                  { in = wo; out = wob; rb = bid - 11264; }
    const int i = (rb * 256 + threadIdx.x) * 4;
    float4 v = *(const float4*)(in + i);
    uint2 pk;
    pk.x = pkbf(v.x, v.y);
    pk.y = pkbf(v.z, v.w);
    *(uint2*)(out + i) = pk;
}

// ---------------------------------------------------------------------------
// QKV projection GEMM v2 (round-9 best-measured config, verbatim):
// qkv[8192][3072] = x[8192][1024] @ w_qkv^T. BM=256 x BN=192 x BK=64,
// 512 thr = 8 waves (2M x 4N), wave tile 128x48. Both-sides swizzle
// (chunk ^= row&7) with pre-swizzled global_load_lds source; double-buffer;
// next tile's DMA issued before compute. grid (16,32)=512 blocks.
// (Round-11's 3-slot counted-vmcnt ring measured NEUTRAL vs this — the
// compiler's own waitcnt placement already governs; keeping the simpler
// proven form.)
// Q-third pre-scaled by 0.125*log2(e); V-third redirected to vT[b,h,d,n].
// ---------------------------------------------------------------------------
__global__ __launch_bounds__(512, 1) void gemm_qkv(
    const unsigned short* __restrict__ A,    // x_bf [8192][1024]
    const unsigned short* __restrict__ Bw,   // wqkv_bf [3072][1024]
    unsigned short* __restrict__ Cb,         // qkv bf16 [8192][3072]
    unsigned short* __restrict__ Vt)         // [B*H][64][2048]
{
    __shared__ unsigned short Ls[2][28672];

    const int tid  = threadIdx.x;
    const int w    = tid >> 6;          // 0..7
    const int lane = tid & 63;
    const int quad = lane >> 4;
    const int l15  = lane & 15;
    const int wm   = w & 1;             // M half (128 rows)
    const int wn   = w >> 1;            // N quarter (48 cols)

    const int lin = blockIdx.y * 16 + blockIdx.x;
    const int swz = (lin & 7) * 64 + (lin >> 3);
    const int m0  = (swz >> 4) * 256;
    const int n0  = (swz & 15) * 192;

    const int r8  = lane >> 3;              // 0..7
    const int chk = (lane & 7) ^ r8;        // pre-swizzled source chunk

    f4v acc[8][3];
    #pragma unroll
    for (int i = 0; i < 8; i++)
        #pragma unroll
        for (int j = 0; j < 3; j++) acc[i][j] = (f4v){0.f, 0.f, 0.f, 0.f};

    #pragma unroll
    for (int j = 0; j < 7; j++) {
        const int u = w * 7 + j;
        const unsigned short* src = (u < 32)
            ? A  + (size_t)(m0 + u * 8 + r8) * 1024 + chk * 8
            : Bw + (size_t)(n0 + (u - 32) * 8 + r8) * 1024 + chk * 8;
        gload_lds16(src, &Ls[0][u * 512]);
    }
    __syncthreads();

    for (int t = 0; t < 16; t++) {
        const int cur = t & 1;

        if (t + 1 < 16) {
            const int k0 = (t + 1) * 64;
            #pragma unroll
            for (int j = 0; j < 7; j++) {
                const int u = w * 7 + j;
                const unsigned short* src = (u < 32)
                    ? A  + (size_t)(m0 + u * 8 + r8) * 1024 + k0 + chk * 8
                    : Bw + (size_t)(n0 + (u - 32) * 8 + r8) * 1024 + k0 + chk * 8;
                gload_lds16(src, &Ls[cur ^ 1][u * 512]);
            }
        }

        #pragma unroll
        for (int s = 0; s < 2; s++) {
            s8v af[8], bf[3];
            #pragma unroll
            for (int ms = 0; ms < 8; ms++) {
                const int row = wm * 128 + ms * 16 + l15;
                af[ms] = *(const s8v*)&Ls[cur][row * 64 + (((s * 4 + quad) ^ (l15 & 7)) * 8)];
            }
            #pragma unroll
            for (int ns = 0; ns < 3; ns++) {
                const int row = 256 + wn * 48 + ns * 16 + l15;
                bf[ns] = *(const s8v*)&Ls[cur][row * 64 + (((s * 4 + quad) ^ (l15 & 7)) * 8)];
            }
            __builtin_amdgcn_s_setprio(1);
            #pragma unroll
            for (int ms = 0; ms < 8; ms++)
                #pragma unroll
                for (int ns = 0; ns < 3; ns++)
                    acc[ms][ns] = __builtin_amdgcn_mfma_f32_16x16x32_bf16(
                        af[ms], bf[ns], acc[ms][ns], 0, 0, 0);
            __builtin_amdgcn_s_setprio(0);
        }

        __syncthreads();
    }

    #pragma unroll
    for (int ns = 0; ns < 3; ns++) {
        const int colb = n0 + wn * 48 + ns * 16;   // wave-uniform, 16-aligned
        if (colb < 2048) {
            const float mul = (colb < 1024) ? 0.18033688011112042f : 1.0f;
            #pragma unroll
            for (int ms = 0; ms < 8; ms++)
                #pragma unroll
                for (int r = 0; r < 4; r++) {
                    const int row = m0 + wm * 128 + ms * 16 + quad * 4 + r;
                    Cb[(size_t)row * E3_ + colb + l15] = f2bf_fast(acc[ms][ns][r] * mul);
                }
        } else {
            const int e = colb + l15 - 2048;
            const int hh = e >> 6, d = e & 63;       // wave-uniform head
            #pragma unroll
            for (int ms = 0; ms < 8; ms++) {
                const int row = m0 + wm * 128 + ms * 16 + quad * 4;  // 4-aligned
                const int bb = row >> 11, nn = row & 2047;
                uint2 pk;
                pk.x = pkbf(acc[ms][ns][0], acc[ms][ns][1]);
                pk.y = pkbf(acc[ms][ns][2], acc[ms][ns][3]);
                *(uint2*)&Vt[(((size_t)bb * 16 + hh) * 64 + d) * 2048 + nn] = pk;
            }
        }
    }
}

// ---------------------------------------------------------------------------
// out projection GEMM v2 (round-9 best-measured config, verbatim):
// out[8192][1024] = ao[8192][1024] @ w_out^T + bias. BM=128 x BN=128 x
// BK=64, 256 thr = 4 waves (2x2), wave tile 64x64, 64 KB LDS -> 2 blk/CU.
// Both-sides swizzle, dbuf, DMA-before-compute. grid (8,64)=512 (%8==0).
// ---------------------------------------------------------------------------
__global__ __launch_bounds__(256, 2) void gemm_out(
    const unsigned short* __restrict__ A,    // ao_bf [8192][1024]
    const unsigned short* __restrict__ Bw,   // wout_bf [1024][1024]
    const float* __restrict__ bias,
    float* __restrict__ Cf)                  // out fp32 [8192][1024]
{
    __shared__ unsigned short Ls[2][16384];

    const int tid  = threadIdx.x;
    const int w    = tid >> 6;          // 0..3
    const int lane = tid & 63;
    const int quad = lane >> 4;
    const int l15  = lane & 15;
    const int wm   = w & 1;             // M half (64 rows)
    const int wn   = w >> 1;            // N half (64 cols)

    const int lin = blockIdx.y * 8 + blockIdx.x;
    const int swz = (lin & 7) * 64 + (lin >> 3);
    const int m0  = (swz >> 3) * 128;
    const int n0  = (swz & 7) * 128;

    const int r8  = lane >> 3;              // 0..7
    const int chk = (lane & 7) ^ r8;        // pre-swizzled source chunk

    f4v acc[4][4];
    #pragma unroll
    for (int i = 0; i < 4; i++)
        #pragma unroll
        for (int j = 0; j < 4; j++) acc[i][j] = (f4v){0.f, 0.f, 0.f, 0.f};

    #pragma unroll
    for (int j = 0; j < 8; j++) {
        const int u = w * 8 + j;
        const unsigned short* src = (u < 16)
            ? A  + (size_t)(m0 + u * 8 + r8) * 1024 + chk * 8
            : Bw + (size_t)(n0 + (u - 16) * 8 + r8) * 1024 + chk * 8;
        gload_lds16(src, &Ls[0][u * 512]);
    }
    __syncthreads();

    for (int t = 0; t < 16; t++) {
        const int cur = t & 1;

        if (t + 1 < 16) {
            const int k0 = (t + 1) * 64;
            #pragma unroll
            for (int j = 0; j < 8; j++) {
                const int u = w * 8 + j;
                const unsigned short* src = (u < 16)
                    ? A  + (size_t)(m0 + u * 8 + r8) * 1024 + k0 + chk * 8
                    : Bw + (size_t)(n0 + (u - 16) * 8 + r8) * 1024 + k0 + chk * 8;
                gload_lds16(src, &Ls[cur ^ 1][u * 512]);
            }
        }

        #pragma unroll
        for (int s = 0; s < 2; s++) {
            s8v af[4], bf[4];
            #pragma unroll
            for (int ms = 0; ms < 4; ms++) {
                const int row = wm * 64 + ms * 16 + l15;
                af[ms] = *(const s8v*)&Ls[cur][row * 64 + (((s * 4 + quad) ^ (l15 & 7)) * 8)];
            }
            #pragma unroll
            for (int ns = 0; ns < 4; ns++) {
                const int row = 128 + wn * 64 + ns * 16 + l15;
                bf[ns] = *(const s8v*)&Ls[cur][row * 64 + (((s * 4 + quad) ^ (l15 & 7)) * 8)];
            }
            __builtin_amdgcn_s_setprio(1);
            #pragma unroll
            for (int ms = 0; ms < 4; ms++)
                #pragma unroll
                for (int ns = 0; ns < 4; ns++)
                    acc[ms][ns] = __builtin_amdgcn_mfma_f32_16x16x32_bf16(
                        af[ms], bf[ns], acc[ms][ns], 0, 0, 0);
            __builtin_amdgcn_s_setprio(0);
        }

        __syncthreads();
    }

    #pragma unroll
    for (int ns = 0; ns < 4; ns++) {
        const float bz = bias[n0 + wn * 64 + ns * 16 + l15];
        #pragma unroll
        for (int ms = 0; ms < 4; ms++)
            #pragma unroll
            for (int r = 0; r < 4; r++) {
                const int row = m0 + wm * 64 + ms * 16 + quad * 4 + r;
                Cf[(size_t)row * 1024 + n0 + wn * 64 + ns * 16 + l15] =
                    acc[ms][ns][r] + bz;
            }
    }
}

// ---------------------------------------------------------------------------
// MFMA flash attention v7 (round-9 best-measured, verbatim — 80us).
// Ceiling note (rounds 9-12): four structural variants (8w/2blk, 8w x 64q,
// 4w/4blk, dual-QK reorder) all land at 80±1us. Counters: MfmaUtil ~47 +
// VALUBusy ~42 + LDS pipe ~65% — three pipes each half-loaded, none
// saturated; the compiler re-serializes source-level reorders (VGPR 60-64).
// Breaking this wall needs the co-designed T2+T3+T4+T5+T10 pipeline as a
// unit, not incremental grafts (each measured null here in isolation).
// 32x32x16, in-register P (cvt_pk + permlane32_swap), 8 waves x 32 q-rows,
// DMA-staged swizzled K/V, dbuf, one barrier/tile, lc-MFMA denominator.
// qkv bf16 [m][3072] (Q pre-scaled by 0.125*log2e); vT[b*16+h][d][n] bf16.
// ---------------------------------------------------------------------------
__global__ __launch_bounds__(512, 4) void attn_mfma(
    const unsigned short* __restrict__ qkv,
    const unsigned short* __restrict__ vT,
    unsigned short* __restrict__ ao)
{
    __shared__ __align__(16) unsigned short Ks[2][64][64];   // [buf][key][d] swz
    __shared__ __align__(16) unsigned short Vs[2][64][64];   // [buf][d][key] swz

    const int tid  = threadIdx.x;
    const int w    = tid >> 6;          // 0..7
    const int lane = tid & 63;
    const int l31  = lane & 31;
    const int hi5  = lane >> 5;         // 0/1
    const int h8   = hi5 * 8;

    const int lin = blockIdx.y * 8 + blockIdx.x;
    const int swz = (lin & 7) * 64 + (lin >> 3);
    const int bx  = swz & 7;
    const int bh  = swz >> 3;
    const int b   = bh >> 4;
    const int h   = bh & 15;
    const int q0  = bx * 256;           // 256 q-rows per block
    const int qb  = q0 + w * 32;        // 32 q-rows per wave

    const unsigned short* qp  = qkv + (size_t)b * N_ * E3_ + (size_t)h * DH_;
    const unsigned short* kp  = qp + 1024;
    const unsigned short* vtp = vT + (size_t)bh * 64 * 2048;

    const int drow = lane >> 3;             // 0..7 within slice
    const int dchk = (lane & 7) ^ drow;     // pre-swizzled source chunk
    const int grow = w * 8 + drow;          // row 0..63 (grow&7 == drow)

    s8v bq[4];
    {
        const unsigned short* qrow = qp + (size_t)(qb + l31) * E3_;
        #pragma unroll
        for (int ks = 0; ks < 4; ks++)
            bq[ks] = *(const s8v*)(qrow + ks * 16 + h8);
    }

    s8v ones;
    #pragma unroll
    for (int i = 0; i < 8; i++) ones[i] = (short)0x3F80;

    const f16v fzero = {0.f,0.f,0.f,0.f,0.f,0.f,0.f,0.f,
                        0.f,0.f,0.f,0.f,0.f,0.f,0.f,0.f};
    f16v o0 = fzero, o1 = fzero;   // d = 0..31 / 32..63
    f16v lc = fzero;               // row-sums, layout-matched to o

    gload_lds16(kp  + (size_t)grow * E3_  + dchk * 8, &Ks[0][w * 8][0]);
    gload_lds16(vtp + (size_t)grow * 2048 + dchk * 8, &Vs[0][w * 8][0]);
    __syncthreads();   // vmcnt(0) drain + barrier

    for (int kt = 0; kt < N_ / 64; kt++) {
        const int cur = kt & 1;

        if (kt + 1 < N_ / 64) {
            const int kn = (kt + 1) * 64;
            gload_lds16(kp  + (size_t)(kn + grow) * E3_  + dchk * 8,
                        &Ks[cur ^ 1][w * 8][0]);
            gload_lds16(vtp + (size_t)grow * 2048 + kn + dchk * 8,
                        &Vs[cur ^ 1][w * 8][0]);
        }

        #pragma unroll
        for (int ksub = 0; ksub < 2; ksub++) {
            const int krow = ksub * 32 + l31;
            const int ksw  = (l31 & 7) * 8;     // krow&7 == l31&7
            s8v ak[4];
            #pragma unroll
            for (int ks = 0; ks < 4; ks++)
                ak[ks] = *(const s8v*)&Ks[cur][krow][(ks * 16 + h8) ^ ksw];

            f16v st = fzero;
            __builtin_amdgcn_s_setprio(1);
            st = __builtin_amdgcn_mfma_f32_32x32x16_bf16(ak[0], bq[0], st, 0, 0, 0);
            st = __builtin_amdgcn_mfma_f32_32x32x16_bf16(ak[1], bq[1], st, 0, 0, 0);
            st = __builtin_amdgcn_mfma_f32_32x32x16_bf16(ak[2], bq[2], st, 0, 0, 0);
            st = __builtin_amdgcn_mfma_f32_32x32x16_bf16(ak[3], bq[3], st, 0, 0, 0);
            __builtin_amdgcn_s_setprio(0);

            float pe[16];
            #pragma unroll
            for (int i = 0; i < 16; i++)
                pe[i] = __builtin_amdgcn_exp2f(st[i]);

            s8v pa[2];
            {
                union { s8v v; unsigned int u[4]; } f0, f1;
                uint2 r;
                r = pl32(cvtpk(pe[0],  pe[1]),  cvtpk(pe[4],  pe[5]));
                f0.u[0] = r.x; f0.u[2] = r.y;
                r = pl32(cvtpk(pe[2],  pe[3]),  cvtpk(pe[6],  pe[7]));
                f0.u[1] = r.x; f0.u[3] = r.y;
                r = pl32(cvtpk(pe[8],  pe[9]),  cvtpk(pe[12], pe[13]));
                f1.u[0] = r.x; f1.u[2] = r.y;
                r = pl32(cvtpk(pe[10], pe[11]), cvtpk(pe[14], pe[15]));
                f1.u[1] = r.x; f1.u[3] = r.y;
                pa[0] = f0.v;   // keys ksub*32 + 0..15
                pa[1] = f1.v;   // keys ksub*32 + 16..31
            }

            #pragma unroll
            for (int j = 0; j < 2; j++) {
                const int kbase = (ksub * 2 + j) * 16 + h8;
                const int vsw   = (l31 & 7) * 8;
                s8v bv0 = *(const s8v*)&Vs[cur][l31     ][kbase ^ vsw];
                s8v bv1 = *(const s8v*)&Vs[cur][32 + l31][kbase ^ vsw];
                __builtin_amdgcn_s_setprio(1);
                o0 = __builtin_amdgcn_mfma_f32_32x32x16_bf16(pa[j], bv0, o0, 0, 0, 0);
                o1 = __builtin_amdgcn_mfma_f32_32x32x16_bf16(pa[j], bv1, o1, 0, 0, 0);
                lc = __builtin_amdgcn_mfma_f32_32x32x16_bf16(pa[j], ones, lc, 0, 0, 0);
                __builtin_amdgcn_s_setprio(0);
            }
        }

        __syncthreads();
    }

    {
        float inv[16];
        #pragma unroll
        for (int r = 0; r < 16; r++) inv[r] = 1.f / lc[r];
        #pragma unroll
        for (int r = 0; r < 16; r++) {
            const int qrow = qb + (r & 3) + 8 * (r >> 2) + 4 * hi5;
            const size_t base = ((size_t)b * N_ + qrow) * (H_ * DH_) + h * DH_;
            ao[base + l31]      = f2bf_fast(o0[r] * inv[r]);
            ao[base + 32 + l31] = f2bf_fast(o1[r] * inv[r]);
        }
    }
}

// ---------------------------------------------------------------------------
// Launch — 4 dispatches
// ---------------------------------------------------------------------------
extern "C" void kernel_launch(void* const* d_in, const int* in_sizes, int n_in,
                              void* d_out, int out_size, void* d_ws, size_t ws_size,
                              hipStream_t stream) {
    const float* x     = (const float*)d_in[0];   // [B,N,DIM]
    const float* w_qkv = (const float*)d_in[1];   // [3072, 1024]
    const float* w_out = (const float*)d_in[2];   // [1024, 1024]
    const float* b_out = (const float*)d_in[3];   // [1024]
    float* out = (float*)d_out;                   // [B,N,DIM] fp32

    char* ws = (char*)d_ws;
    unsigned short* x_bf    = (unsigned short*)(ws);                        // 16 MB
    unsigned short* wqkv_bf = (unsigned short*)(ws + (((size_t)16) << 20)); //  6 MB
    unsigned short* wout_bf = (unsigned short*)(ws + (((size_t)22) << 20)); //  2 MB
    unsigned short* qkv_bf  = (unsigned short*)(ws + (((size_t)24) << 20)); // 48 MB
    unsigned short* vT      = (unsigned short*)(ws + (((size_t)72) << 20)); // 16 MB
    unsigned short* ao_bf   = (unsigned short*)(ws + (((size_t)88) << 20)); // 16 MB

    const int M = B_ * N_;   // 8192

    // 0) fused input conversions fp32 -> bf16 (1 dispatch)
    cvt_all<<<12288, 256, 0, stream>>>(x, w_qkv, w_out, x_bf, wqkv_bf, wout_bf);

    // 1) QKV projection v2: 256x192x64 tiles, dbuf+prefetch, swizzled LDS
    {
        dim3 grid(E3_ / 192, M / 256);   // (16, 32) = 512 blocks
        gemm_qkv<<<grid, 512, 0, stream>>>(x_bf, wqkv_bf, qkv_bf, vT);
    }
    // 2) attention v7: 8 waves x 32 q-rows, 2 blocks/CU (80us best)
    {
        dim3 grid(N_ / 256, B_ * H_);    // (8, 64) = 512 blocks
        attn_mfma<<<grid, 512, 0, stream>>>(qkv_bf, vT, ao_bf);
    }
    // 3) out projection v2: 128x128x64 tiles, 2 blocks/CU, dbuf+prefetch
    {
        dim3 grid(DIM_ / 128, M / 128);  // (8, 64) = 512 blocks (%8==0)
        gemm_out<<<grid, 256, 0, stream>>>(ao_bf, wout_bf, b_out, out);
    }
    (void)in_sizes; (void)n_in; (void)out_size; (void)ws_size;
}